// Round 16
// baseline (248.180 us; speedup 1.0000x reference)
//
#include <hip/hip_runtime.h>
#include <math.h>

typedef unsigned short u16;
typedef __attribute__((ext_vector_type(8))) short bf16x8;   // 8 bf16 = 4 VGPRs (MFMA A/B frag)
typedef __attribute__((ext_vector_type(4))) float f32x4;    // MFMA C/D frag

#define NB 1024          // graphs
#define NS 48            // nodes per graph
#define ND 256           // input dim
#define NN (NB*NS)       // 49152 nodes
#define NE (4*NN)        // 196608 edges
#define GD 512           // graph_dim
#define KK 1024          // GEMM K (interleaved [self | agg] per row)

__device__ __forceinline__ void gld16(const void* g, void* l) {
  __builtin_amdgcn_global_load_lds(
      (const __attribute__((address_space(1))) void*)(void*)g,
      (__attribute__((address_space(3))) void*)l, 16, 0, 0);
}

__device__ __forceinline__ float bf2f(u16 h) {
  unsigned u = ((unsigned)h) << 16; float f; __builtin_memcpy(&f, &u, 4); return f;
}
__device__ __forceinline__ u16 f2bf(float f) {
  unsigned u; __builtin_memcpy(&u, &f, 4);
  u += 0x7fffu + ((u >> 16) & 1u);           // RNE (hand-rolled: no NaN branch, 3 ops)
  return (u16)(u >> 16);
}
__device__ __forceinline__ void unpack8(uint4 v, float* f) {
  f[0]=bf2f((u16)(v.x & 0xffff)); f[1]=bf2f((u16)(v.x >> 16));
  f[2]=bf2f((u16)(v.y & 0xffff)); f[3]=bf2f((u16)(v.y >> 16));
  f[4]=bf2f((u16)(v.z & 0xffff)); f[5]=bf2f((u16)(v.z >> 16));
  f[6]=bf2f((u16)(v.w & 0xffff)); f[7]=bf2f((u16)(v.w >> 16));
}
__device__ __forceinline__ uint4 pack8(const float* f) {
  uint4 v;
  v.x = (unsigned)f2bf(f[0]) | ((unsigned)f2bf(f[1]) << 16);
  v.y = (unsigned)f2bf(f[2]) | ((unsigned)f2bf(f[3]) << 16);
  v.z = (unsigned)f2bf(f[4]) | ((unsigned)f2bf(f[5]) << 16);
  v.w = (unsigned)f2bf(f[6]) | ((unsigned)f2bf(f[7]) << 16);
  return v;
}

// ---------- fused: edge histograms + weight bf16-cat + x -> xcomb[:,0:256] ----------
// blocks 0..767: hist; 768..1791: W1cat/W2cat; 1792..7935: x conversion
__global__ void k_wxh(const int* __restrict__ ei, int* __restrict__ deg, int* __restrict__ cnt,
                      const float* __restrict__ Wr1, const float* __restrict__ Wl1,
                      const float* __restrict__ Wr2, const float* __restrict__ Wl2,
                      u16* __restrict__ W1c, u16* __restrict__ W2c,
                      const float* __restrict__ x, u16* __restrict__ xcomb) {
  const int b = blockIdx.x;
  if (b < 768) {
    int e = b * 256 + threadIdx.x;
    atomicAdd(&deg[ei[e]], 1);        // out-degree (row)
    atomicAdd(&cnt[ei[NE + e]], 1);   // in-degree  (col)
  } else if (b < 1792) {
    const int b2 = b - 768;
    const float* Wr = (b2 < 512) ? Wr1 : Wr2;
    const float* Wl = (b2 < 512) ? Wl1 : Wl2;
    u16* Wc = (b2 < 512) ? W1c : W2c;
    int i = ((b2 & 511) * 256 + threadIdx.x) * 4;   // flat over 512*1024
    int n = i >> 10, k = i & 1023;
    const float* src = (k < 512) ? (Wr + n * 512 + k) : (Wl + n * 512 + (k - 512));
    float4 v = *(const float4*)src;
    ushort4 h; h.x = f2bf(v.x); h.y = f2bf(v.y); h.z = f2bf(v.z); h.w = f2bf(v.w);
    *(ushort4*)(Wc + i) = h;
  } else {
    int i = ((b - 1792) * 256 + threadIdx.x) * 8;   // flat over NN*256
    int node = i >> 8, col = i & 255;
    float4 v0 = *(const float4*)(x + i);
    float4 v1 = *(const float4*)(x + i + 4);
    float f[8] = {v0.x, v0.y, v0.z, v0.w, v1.x, v1.y, v1.z, v1.w};
    *(uint4*)(xcomb + (size_t)node * KK + col) = pack8(f);
  }
}

// ---------- hierarchical exclusive scan (coalesced, 3 kernels) ----------
// A: 96 blocks x 256t. b<48: deg-tile sums (+fused dinv); b>=48: cnt-tile sums.
__global__ void k_bsum(const int* __restrict__ deg, const int* __restrict__ cnt,
                       float* __restrict__ dinv, int* __restrict__ bsum) {
  const int b = blockIdx.x, t = threadIdx.x;
  const int lane = t & 63, wid = t >> 6;
  const bool isDeg = b < 48;
  const int base = (isDeg ? b : b - 48) * 1024 + t * 4;
  const int4 v = *(const int4*)((isDeg ? deg : cnt) + base);
  if (isDeg) {
    float4 dv;
    dv.x = (v.x > 0) ? rsqrtf((float)v.x) : 0.f;
    dv.y = (v.y > 0) ? rsqrtf((float)v.y) : 0.f;
    dv.z = (v.z > 0) ? rsqrtf((float)v.z) : 0.f;
    dv.w = (v.w > 0) ? rsqrtf((float)v.w) : 0.f;
    *(float4*)(dinv + base) = dv;
  }
  int s = v.x + v.y + v.z + v.w;
  #pragma unroll
  for (int off = 32; off > 0; off >>= 1) s += __shfl_down(s, off, 64);
  __shared__ int ws[4];
  if (lane == 0) ws[wid] = s;
  __syncthreads();
  if (t == 0) bsum[b] = ws[0] + ws[1] + ws[2] + ws[3];
}

// B: 1 block x 128t; wave 0 scans deg block-sums, wave 1 scans cnt block-sums.
__global__ void k_bscan(const int* __restrict__ bsum, int* __restrict__ bscan,
                        int* __restrict__ rowOff, int* __restrict__ colOff) {
  const int t = threadIdx.x, w = t >> 6, lane = t & 63;
  const int s = (lane < 48) ? bsum[w * 48 + lane] : 0;
  int incl = s;
  #pragma unroll
  for (int off = 1; off < 64; off <<= 1) {
    int v = __shfl_up(incl, off, 64);
    if (lane >= off) incl += v;
  }
  if (lane < 48) bscan[w * 48 + lane] = incl - s;
  if (lane == 47) { if (w == 0) rowOff[NN] = incl; else colOff[NN] = incl; }
}

// C: 96 blocks x 256t; block-local scan (int4 + wave shfl + LDS) + bscan offset.
__global__ void k_scanout(const int* __restrict__ deg, const int* __restrict__ cnt,
                          const int* __restrict__ bscan,
                          int* __restrict__ rowOff, int* __restrict__ colOff) {
  const int b = blockIdx.x, t = threadIdx.x;
  const int lane = t & 63, wid = t >> 6;
  const bool isDeg = b < 48;
  const int base = (isDeg ? b : b - 48) * 1024 + t * 4;
  const int4 v = *(const int4*)((isDeg ? deg : cnt) + base);
  const int s = v.x + v.y + v.z + v.w;
  int incl = s;
  #pragma unroll
  for (int off = 1; off < 64; off <<= 1) {
    int u = __shfl_up(incl, off, 64);
    if (lane >= off) incl += u;
  }
  __shared__ int ws[4];
  if (lane == 63) ws[wid] = incl;
  __syncthreads();
  int woff = bscan[b];
  for (int i = 0; i < wid; ++i) woff += ws[i];
  const int e0 = incl - s + woff;
  int4 o;
  o.x = e0; o.y = e0 + v.x; o.z = o.y + v.y; o.w = o.z + v.z;
  *(int4*)((isDeg ? rowOff : colOff) + base) = o;
}

__global__ void k_fill(const int* __restrict__ ei,
                       const int* __restrict__ rowOff, const int* __restrict__ colOff,
                       int* __restrict__ rowFill, int* __restrict__ colFill,
                       int* __restrict__ rowCol, int* __restrict__ colSrc) {
  int e = blockIdx.x * 256 + threadIdx.x;
  if (e < NE) {
    int r = ei[e], c = ei[NE + e];
    int pr = atomicAdd(&rowFill[r], 1);
    rowCol[rowOff[r] + pr] = c;            // row-CSR: dst list per src (Laplacian)
    int pc = atomicAdd(&colFill[c], 1);
    colSrc[colOff[c] + pc] = r;            // col-CSR: src list per dst (SAGE agg)
  }
}

// xcomb[i,256:512] = x[i] - dinv[i]*sum_{row-CSR} dinv[c]*x[c]  (x read from xcomb[.,0:256])
// Wave-uniform guards: tail chunks SKIP the gather (no clamped waste loads).
__global__ void k_lap(u16* __restrict__ xcomb, const int* __restrict__ rowOff,
                      const int* __restrict__ rowCol, const float* __restrict__ dinv) {
  const int gid = blockIdx.x * 256 + threadIdx.x;
  const int wid = gid >> 6, lane = gid & 63;
  const int node = wid * 2 + (lane >> 5);
  const int f0 = (lane & 31) * 8;                   // 8 feats/lane, 32 lanes cover 256
  float xi[8]; unpack8(*(const uint4*)(xcomb + (size_t)node * KK + f0), xi);
  float a[8] = {};
  const int s0 = rowOff[node], s1 = rowOff[node + 1];
  for (int p = s0; p < s1; p += 4) {
    uint4 g[4] = {};                                // zero: skipped -> +0 contribution
    float w[4] = {};
    #pragma unroll
    for (int i = 0; i < 4; ++i) {
      if (p + i < s1) {                             // wave-uniform guard
        const int c = rowCol[p + i];
        w[i] = dinv[c];
        g[i] = *(const uint4*)(xcomb + (size_t)c * KK + f0);
      }
    }
    #pragma unroll
    for (int i = 0; i < 4; ++i) {
      float tmp[8]; unpack8(g[i], tmp);
      #pragma unroll
      for (int j = 0; j < 8; ++j) a[j] += w[i] * tmp[j];
    }
  }
  const float di = dinv[node];
  float l[8];
  #pragma unroll
  for (int j = 0; j < 8; ++j) l[j] = xi[j] - di * a[j];
  *(uint4*)(xcomb + (size_t)node * KK + ND + f0) = pack8(l);
}

// xcomb[i, 512:1024] = (1/cnt_i) * sum_{src->i} xcomb[src, 0:512]
// TWO nodes per wave; tail chunks SKIP gathers (uniform guards, zero-init regs).
__global__ void k_aggx(u16* __restrict__ xcomb, const int* __restrict__ colOff,
                       const int* __restrict__ colSrc) {
  const int gid = blockIdx.x * 256 + threadIdx.x;
  const int wid = gid >> 6, lane = gid & 63;
  const int n0 = wid * 2, n1 = n0 + 1;
  const int f0 = lane * 8;                          // 64 lanes cover 512 cols
  const int sA = colOff[n0], sB = colOff[n0 + 1], eB = colOff[n1 + 1];
  const int dA = sB - sA, dB = eB - sB;
  float accA[8] = {}, accB[8] = {};
  const int T = (dA > dB) ? dA : dB;
  for (int t = 0; t < T; t += 4) {
    uint4 gA[4] = {}, gB[4] = {};                   // zero: skipped -> +0
    #pragma unroll
    for (int i = 0; i < 4; ++i) {
      const int o = t + i;
      if (o < dA) gA[i] = *(const uint4*)(xcomb + (size_t)colSrc[sA + o] * KK + f0);
      if (o < dB) gB[i] = *(const uint4*)(xcomb + (size_t)colSrc[sB + o] * KK + f0);
    }
    #pragma unroll
    for (int i = 0; i < 4; ++i) {
      float tmp[8];
      unpack8(gA[i], tmp);
      #pragma unroll
      for (int j = 0; j < 8; ++j) accA[j] += tmp[j];
      unpack8(gB[i], tmp);
      #pragma unroll
      for (int j = 0; j < 8; ++j) accB[j] += tmp[j];
    }
  }
  const float invA = (dA > 0) ? 1.0f / (float)dA : 1.0f;
  const float invB = (dB > 0) ? 1.0f / (float)dB : 1.0f;
  float rA[8], rB[8];
  #pragma unroll
  for (int j = 0; j < 8; ++j) { rA[j] = accA[j] * invA; rB[j] = accB[j] * invB; }
  *(uint4*)(xcomb + (size_t)n0 * KK + 512 + f0) = pack8(rA);
  *(uint4*)(xcomb + (size_t)n1 * KK + 512 + f0) = pack8(rB);
}

// ---------- GEMM1: h[M,512] = gelu(A[M,1024] @ B[512,1024]^T + b1), bf16 out ----------
// 128x128 tile, 8 waves (2x4, 64x32 sub-tiles), BK=64, single-buffer LDS 2-phase.
// 8-slot XOR swizzle both-sides; flip'd fragment offsets hoisted (static addresses).
__global__ __launch_bounds__(512, 4) void k_gemm1(const u16* __restrict__ A,
                                                  const u16* __restrict__ Bw,
                                                  const float* __restrict__ bias,
                                                  u16* __restrict__ Out) {
  __shared__ u16 As[128 * 64];
  __shared__ u16 Bs[128 * 64];
  const int tid = threadIdx.x;
  const int w = tid >> 6, lane = tid & 63;
  const int wr = w >> 2, wc = w & 3;       // 2 x 4 waves of 64x32

  const int cpx = gridDim.x >> 3;
  const int o = blockIdx.x;
  const int swz = (o & 7) * cpx + (o >> 3);
  const int bx = swz >> 2;                 // M tile
  const int by = swz & 3;                  // N tile

  const int lrow = lane >> 3;
  const int lcol = ((lane & 7) ^ lrow) * 8;          // XOR slot swizzle (row&7 = lrow)
  const u16* Ag = A  + (size_t)(bx * 128 + w * 16 + lrow) * KK + lcol;
  const u16* Bg = Bw + (size_t)(by * 128 + w * 16 + lrow) * KK + lcol;
  u16* Asl = As + w * 16 * 64;
  u16* Bsl = Bs + w * 16 * 64;

  const int kg = lane >> 4;
  const int slot = (kg ^ (lane & 7)) * 8;
  const int aoff0 = (wr * 64 + (lane & 15)) * 64 + slot;
  const int boff0 = (wc * 32 + (lane & 15)) * 64 + slot;
  const int aoff1 = aoff0 ^ 32;            // s2=1 half (bit5 flip, no carries)
  const int boff1 = boff0 ^ 32;

  f32x4 acc[4][2] = {};

  for (int kt = 0; kt < KK; kt += 64) {
    gld16(Ag + kt, Asl);
    gld16(Ag + kt + 8 * KK, Asl + 8 * 64);
    gld16(Bg + kt, Bsl);
    gld16(Bg + kt + 8 * KK, Bsl + 8 * 64);
    __syncthreads();
    {
      bf16x8 aF[4], bF[2];
      #pragma unroll
      for (int i = 0; i < 4; ++i) aF[i] = *(const bf16x8*)(As + aoff0 + i * 1024);
      #pragma unroll
      for (int i = 0; i < 2; ++i) bF[i] = *(const bf16x8*)(Bs + boff0 + i * 1024);
      #pragma unroll
      for (int mi = 0; mi < 4; ++mi)
        #pragma unroll
        for (int ni = 0; ni < 2; ++ni)
          acc[mi][ni] = __builtin_amdgcn_mfma_f32_16x16x32_bf16(aF[mi], bF[ni], acc[mi][ni], 0, 0, 0);
    }
    {
      bf16x8 aF[4], bF[2];
      #pragma unroll
      for (int i = 0; i < 4; ++i) aF[i] = *(const bf16x8*)(As + aoff1 + i * 1024);
      #pragma unroll
      for (int i = 0; i < 2; ++i) bF[i] = *(const bf16x8*)(Bs + boff1 + i * 1024);
      #pragma unroll
      for (int mi = 0; mi < 4; ++mi)
        #pragma unroll
        for (int ni = 0; ni < 2; ++ni)
          acc[mi][ni] = __builtin_amdgcn_mfma_f32_16x16x32_bf16(aF[mi], bF[ni], acc[mi][ni], 0, 0, 0);
    }
    __syncthreads();
  }

  // C/D layout: col = lane&15, row = (lane>>4)*4 + r
  const int lc = lane & 15, lr = (lane >> 4) * 4;
  const size_t r0 = (size_t)bx * 128 + wr * 64;
  const int cb = by * 128 + wc * 32;
  float bv[2];
  #pragma unroll
  for (int ni = 0; ni < 2; ++ni) bv[ni] = bias[cb + ni * 16 + lc];
  #pragma unroll
  for (int mi = 0; mi < 4; ++mi)
    #pragma unroll
    for (int ni = 0; ni < 2; ++ni)
      #pragma unroll
      for (int r = 0; r < 4; ++r) {
        float v = acc[mi][ni][r] + bv[ni];
        v = 0.5f * v * (1.0f + erff(v * 0.70710678118654752f));   // exact gelu
        Out[(r0 + mi * 16 + lr + r) * GD + (cb + ni * 16 + lc)] = f2bf(v);
      }
}

// ---------- GEMM2: out[1024,512] += split-K partials (f32 atomics) ----------
__global__ __launch_bounds__(256, 4) void k_gemm2(const u16* __restrict__ A,
                                                  const u16* __restrict__ Bw,
                                                  const float* __restrict__ bias,
                                                  float* __restrict__ Out) {
  __shared__ u16 As[128 * 64];
  __shared__ u16 Bs[128 * 64];
  const int tid = threadIdx.x;
  const int w = tid >> 6, lane = tid & 63;
  const int wr = w >> 1, wc = w & 1;
  const int bid = blockIdx.x;
  const int ks = bid >> 5;                 // 8 K-splits
  const int rr = bid & 31;
  const int bx = rr >> 2;                  // 8 M tiles
  const int by = rr & 3;                   // 4 N tiles

  const int lrow = lane >> 3;
  const int lcol = ((lane & 7) ^ lrow) * 8;
  const u16* Ag = A  + (size_t)(bx * 128 + w * 32 + lrow) * KK + lcol + ks * 128;
  const u16* Bg = Bw + (size_t)(by * 128 + w * 32 + lrow) * KK + lcol + ks * 128;
  u16* Asl = As + w * 32 * 64;
  u16* Bsl = Bs + w * 32 * 64;

  const int kg = lane >> 4;
  const int slot = (kg ^ (lane & 7)) * 8;
  const int aoff0 = (wr * 64 + (lane & 15)) * 64 + slot;
  const int boff0 = (wc * 64 + (lane & 15)) * 64 + slot;
  const int aoff1 = aoff0 ^ 32;
  const int boff1 = boff0 ^ 32;

  f32x4 acc[4][4] = {};

  #pragma unroll
  for (int kt = 0; kt < 128; kt += 64) {
    #pragma unroll
    for (int c = 0; c < 4; ++c) {
      gld16(Ag + kt + c * 8 * KK, Asl + c * 8 * 64);
      gld16(Bg + kt + c * 8 * KK, Bsl + c * 8 * 64);
    }
    __syncthreads();
    {
      bf16x8 aF[4], bF[4];
      #pragma unroll
      for (int i = 0; i < 4; ++i) aF[i] = *(const bf16x8*)(As + aoff0 + i * 1024);
      #pragma unroll
      for (int i = 0; i < 4; ++i) bF[i] = *(const bf16x8*)(Bs + boff0 + i * 1024);
      #pragma unroll
      for (int mi = 0; mi < 4; ++mi)
        #pragma unroll
        for (int ni = 0; ni < 4; ++ni)
          acc[mi][ni] = __builtin_amdgcn_mfma_f32_16x16x32_bf16(aF[mi], bF[ni], acc[mi][ni], 0, 0, 0);
    }
    {
      bf16x8 aF[4], bF[4];
      #pragma unroll
      for (int i = 0; i < 4; ++i) aF[i] = *(const bf16x8*)(As + aoff1 + i * 1024);
      #pragma unroll
      for (int i = 0; i < 4; ++i) bF[i] = *(const bf16x8*)(Bs + boff1 + i * 1024);
      #pragma unroll
      for (int mi = 0; mi < 4; ++mi)
        #pragma unroll
        for (int ni = 0; ni < 4; ++ni)
          acc[mi][ni] = __builtin_amdgcn_mfma_f32_16x16x32_bf16(aF[mi], bF[ni], acc[mi][ni], 0, 0, 0);
    }
    __syncthreads();
  }

  const int lc = lane & 15, lr = (lane >> 4) * 4;
  const size_t r0 = (size_t)bx * 128 + wr * 64;
  const int cb = by * 128 + wc * 64;
  float bv[4];
  #pragma unroll
  for (int ni = 0; ni < 4; ++ni) bv[ni] = (ks == 0) ? bias[cb + ni * 16 + lc] : 0.0f;
  #pragma unroll
  for (int mi = 0; mi < 4; ++mi)
    #pragma unroll
    for (int ni = 0; ni < 4; ++ni)
      #pragma unroll
      for (int r = 0; r < 4; ++r)
        atomicAdd(&Out[(r0 + mi * 16 + lr + r) * GD + (cb + ni * 16 + lc)],
                  acc[mi][ni][r] + bv[ni]);
}

// fused agg2 + pool -> h2cat[g, 0:512]=mean_pool(h), [512:1024]=mean_pool(mean_agg(h))
// Tail chunks SKIP gathers (uniform guards, zero-init regs).
__global__ __launch_bounds__(512) void k_aggh(const u16* __restrict__ h, const int* __restrict__ colOff,
                                              const int* __restrict__ colSrc,
                                              u16* __restrict__ h2cat) {
  __shared__ float red[2][8][GD];                    // 32 KB
  const int g = blockIdx.x;
  const int t = threadIdx.x, w = t >> 6, lane = t & 63;
  const int f0 = lane * 8;
  float pr[8] = {}, pa[8] = {};
  for (int n = w; n < NS; n += 16) {                 // pairs (n, n+8); w in [0,8)
    const int node0 = g * NS + n, node1 = node0 + 8;
    float tmp[8];
    unpack8(*(const uint4*)(h + (size_t)node0 * GD + f0), tmp);
    #pragma unroll
    for (int j = 0; j < 8; ++j) pr[j] += tmp[j];
    unpack8(*(const uint4*)(h + (size_t)node1 * GD + f0), tmp);
    #pragma unroll
    for (int j = 0; j < 8; ++j) pr[j] += tmp[j];
    const int sA = colOff[node0], eA = colOff[node0 + 1];
    const int sB = colOff[node1], eB = colOff[node1 + 1];
    const int dA = eA - sA, dB = eB - sB;
    float accA[8] = {}, accB[8] = {};
    const int T = (dA > dB) ? dA : dB;
    for (int p = 0; p < T; p += 4) {
      uint4 gA[4] = {}, gB[4] = {};
      #pragma unroll
      for (int i = 0; i < 4; ++i) {
        const int oo = p + i;
        if (oo < dA) gA[i] = *(const uint4*)(h + (size_t)colSrc[sA + oo] * GD + f0);
        if (oo < dB) gB[i] = *(const uint4*)(h + (size_t)colSrc[sB + oo] * GD + f0);
      }
      #pragma unroll
      for (int i = 0; i < 4; ++i) {
        unpack8(gA[i], tmp);
        #pragma unroll
        for (int j = 0; j < 8; ++j) accA[j] += tmp[j];
        unpack8(gB[i], tmp);
        #pragma unroll
        for (int j = 0; j < 8; ++j) accB[j] += tmp[j];
      }
    }
    const float invA = (dA > 0) ? 1.0f / (float)dA : 1.0f;
    const float invB = (dB > 0) ? 1.0f / (float)dB : 1.0f;
    #pragma unroll
    for (int j = 0; j < 8; ++j) pa[j] += accA[j] * invA;
    #pragma unroll
    for (int j = 0; j < 8; ++j) pa[j] += accB[j] * invB;
  }
  #pragma unroll
  for (int j = 0; j < 8; ++j) { red[0][w][f0 + j] = pr[j]; red[1][w][f0 + j] = pa[j]; }
  __syncthreads();
  if (t < 256) {
    const int f = t * 2;                             // 256 threads x 2 feats
    const float invS = 1.0f / (float)NS;
    float r0 = 0.f, r1 = 0.f, a0 = 0.f, a1 = 0.f;
    #pragma unroll
    for (int ww = 0; ww < 8; ++ww) {
      r0 += red[0][ww][f]; r1 += red[0][ww][f + 1];
      a0 += red[1][ww][f]; a1 += red[1][ww][f + 1];
    }
    r0 *= invS; r1 *= invS; a0 *= invS; a1 *= invS;
    *(unsigned*)(h2cat + (size_t)g * KK + f)       = (unsigned)f2bf(r0) | ((unsigned)f2bf(r1) << 16);
    *(unsigned*)(h2cat + (size_t)g * KK + 512 + f) = (unsigned)f2bf(a0) | ((unsigned)f2bf(a1) << 16);
  }
}

extern "C" void kernel_launch(void* const* d_in, const int* in_sizes, int n_in,
                              void* d_out, int out_size, void* d_ws, size_t ws_size,
                              hipStream_t stream) {
  const float* x   = (const float*)d_in[0];
  const int*   ei  = (const int*)d_in[1];           // int64 in reference -> int32 on device
  const float* Wl1 = (const float*)d_in[2];
  const float* Wr1 = (const float*)d_in[3];
  const float* b1  = (const float*)d_in[4];
  const float* Wl2 = (const float*)d_in[5];
  const float* Wr2 = (const float*)d_in[6];
  const float* b2  = (const float*)d_in[7];
  float* out = (float*)d_out;
  (void)in_sizes; (void)n_in; (void)out_size; (void)ws_size;

  // ---- workspace layout ----
  int* deg     = (int*)d_ws;                 // NN
  int* cnt     = deg + NN;                   // NN
  int* rowFill = cnt + NN;                   // NN
  int* colFill = rowFill + NN;               // NN   (deg..colFill = one memset region)
  int* rowOff  = colFill + NN;               // NN+64
  int* colOff  = rowOff + NN + 64;           // NN+64
  float* dinv  = (float*)(colOff + NN + 64); // NN
  int* rowCol  = (int*)(dinv + NN);          // NE
  int* colSrc  = rowCol + NE;                // NE
  int* bsum    = colSrc + NE;                // 96 (+pad)
  int* bscan   = bsum + 128;                 // 96 (+pad)
  u16* W1c     = (u16*)(bscan + 128);        // 512*1024 ([Wr1|Wl1] per row)
  u16* W2c     = W1c + 512 * KK;             // 512*1024
  u16* h2cat   = W2c + 512 * KK;             // 1024*1024
  u16* xcomb   = h2cat + (size_t)NB * KK;    // NN*1024 ([x|lap | agg] per row)
  u16* h       = xcomb + (size_t)NN * KK;    // NN*512

  hipMemsetAsync(deg, 0, sizeof(int) * 4 * NN, stream);
  hipMemsetAsync(out, 0, (size_t)NB * GD * sizeof(float), stream);   // split-K accumulator

  k_wxh<<<7936, 256, 0, stream>>>(ei, deg, cnt, Wr1, Wl1, Wr2, Wl2, W1c, W2c, x, xcomb);
  k_bsum<<<96, 256, 0, stream>>>(deg, cnt, dinv, bsum);
  k_bscan<<<1, 128, 0, stream>>>(bsum, bscan, rowOff, colOff);
  k_scanout<<<96, 256, 0, stream>>>(deg, cnt, bscan, rowOff, colOff);
  k_fill<<<NE / 256, 256, 0, stream>>>(ei, rowOff, colOff, rowFill, colFill, rowCol, colSrc);
  k_lap<<<(NN * 32) / 256, 256, 0, stream>>>(xcomb, rowOff, rowCol, dinv);
  k_aggx<<<(NN * 32) / 256, 256, 0, stream>>>(xcomb, colOff, colSrc);

  // h = gelu(xcomb @ W1c^T + b1): M=49152, N=512, K=1024
  k_gemm1<<<(NN / 128) * 4, 512, 0, stream>>>(xcomb, W1c, b1, h);

  k_aggh<<<NB, 512, 0, stream>>>(h, colOff, colSrc, h2cat);

  // out += split-K partials of h2cat @ W2c^T (+b2 from ks==0): M=1024, N=512
  k_gemm2<<<256, 256, 0, stream>>>(h2cat, W2c, b2, out);
}

// Round 17
// 237.484 us; speedup vs baseline: 1.0450x; 1.0450x over previous
//
#include <hip/hip_runtime.h>
#include <math.h>

typedef unsigned short u16;
typedef __attribute__((ext_vector_type(8))) short bf16x8;   // 8 bf16 = 4 VGPRs (MFMA A/B frag)
typedef __attribute__((ext_vector_type(4))) float f32x4;    // MFMA C/D frag

#define NB 1024          // graphs
#define NS 48            // nodes per graph
#define ND 256           // input dim
#define NN (NB*NS)       // 49152 nodes
#define NE (4*NN)        // 196608 edges
#define GD 512           // graph_dim
#define KK 1024          // GEMM K (interleaved [self | agg] per row)

__device__ __forceinline__ void gld16(const void* g, void* l) {
  __builtin_amdgcn_global_load_lds(
      (const __attribute__((address_space(1))) void*)(void*)g,
      (__attribute__((address_space(3))) void*)l, 16, 0, 0);
}

__device__ __forceinline__ float bf2f(u16 h) {
  unsigned u = ((unsigned)h) << 16; float f; __builtin_memcpy(&f, &u, 4); return f;
}
__device__ __forceinline__ u16 f2bf(float f) {
  unsigned u; __builtin_memcpy(&u, &f, 4);
  u += 0x7fffu + ((u >> 16) & 1u);           // RNE (hand-rolled: no NaN branch, 3 ops)
  return (u16)(u >> 16);
}
__device__ __forceinline__ void unpack8(uint4 v, float* f) {
  f[0]=bf2f((u16)(v.x & 0xffff)); f[1]=bf2f((u16)(v.x >> 16));
  f[2]=bf2f((u16)(v.y & 0xffff)); f[3]=bf2f((u16)(v.y >> 16));
  f[4]=bf2f((u16)(v.z & 0xffff)); f[5]=bf2f((u16)(v.z >> 16));
  f[6]=bf2f((u16)(v.w & 0xffff)); f[7]=bf2f((u16)(v.w >> 16));
}
__device__ __forceinline__ uint4 pack8(const float* f) {
  uint4 v;
  v.x = (unsigned)f2bf(f[0]) | ((unsigned)f2bf(f[1]) << 16);
  v.y = (unsigned)f2bf(f[2]) | ((unsigned)f2bf(f[3]) << 16);
  v.z = (unsigned)f2bf(f[4]) | ((unsigned)f2bf(f[5]) << 16);
  v.w = (unsigned)f2bf(f[6]) | ((unsigned)f2bf(f[7]) << 16);
  return v;
}

// ---------- fused: edge histograms + weight bf16-cat + x -> xcomb[:,0:256] ----------
// blocks 0..767: hist; 768..1791: W1cat/W2cat; 1792..7935: x conversion
__global__ void k_wxh(const int* __restrict__ ei, int* __restrict__ deg, int* __restrict__ cnt,
                      const float* __restrict__ Wr1, const float* __restrict__ Wl1,
                      const float* __restrict__ Wr2, const float* __restrict__ Wl2,
                      u16* __restrict__ W1c, u16* __restrict__ W2c,
                      const float* __restrict__ x, u16* __restrict__ xcomb) {
  const int b = blockIdx.x;
  if (b < 768) {
    int e = b * 256 + threadIdx.x;
    atomicAdd(&deg[ei[e]], 1);        // out-degree (row)
    atomicAdd(&cnt[ei[NE + e]], 1);   // in-degree  (col)
  } else if (b < 1792) {
    const int b2 = b - 768;
    const float* Wr = (b2 < 512) ? Wr1 : Wr2;
    const float* Wl = (b2 < 512) ? Wl1 : Wl2;
    u16* Wc = (b2 < 512) ? W1c : W2c;
    int i = ((b2 & 511) * 256 + threadIdx.x) * 4;   // flat over 512*1024
    int n = i >> 10, k = i & 1023;
    const float* src = (k < 512) ? (Wr + n * 512 + k) : (Wl + n * 512 + (k - 512));
    float4 v = *(const float4*)src;
    ushort4 h; h.x = f2bf(v.x); h.y = f2bf(v.y); h.z = f2bf(v.z); h.w = f2bf(v.w);
    *(ushort4*)(Wc + i) = h;
  } else {
    int i = ((b - 1792) * 256 + threadIdx.x) * 8;   // flat over NN*256
    int node = i >> 8, col = i & 255;
    float4 v0 = *(const float4*)(x + i);
    float4 v1 = *(const float4*)(x + i + 4);
    float f[8] = {v0.x, v0.y, v0.z, v0.w, v1.x, v1.y, v1.z, v1.w};
    *(uint4*)(xcomb + (size_t)node * KK + col) = pack8(f);
  }
}

// ---------- hierarchical exclusive scan (coalesced, 3 kernels) ----------
// A: 96 blocks x 256t. b<48: deg-tile sums (+fused dinv); b>=48: cnt-tile sums.
__global__ void k_bsum(const int* __restrict__ deg, const int* __restrict__ cnt,
                       float* __restrict__ dinv, int* __restrict__ bsum) {
  const int b = blockIdx.x, t = threadIdx.x;
  const int lane = t & 63, wid = t >> 6;
  const bool isDeg = b < 48;
  const int base = (isDeg ? b : b - 48) * 1024 + t * 4;
  const int4 v = *(const int4*)((isDeg ? deg : cnt) + base);
  if (isDeg) {
    float4 dv;
    dv.x = (v.x > 0) ? rsqrtf((float)v.x) : 0.f;
    dv.y = (v.y > 0) ? rsqrtf((float)v.y) : 0.f;
    dv.z = (v.z > 0) ? rsqrtf((float)v.z) : 0.f;
    dv.w = (v.w > 0) ? rsqrtf((float)v.w) : 0.f;
    *(float4*)(dinv + base) = dv;
  }
  int s = v.x + v.y + v.z + v.w;
  #pragma unroll
  for (int off = 32; off > 0; off >>= 1) s += __shfl_down(s, off, 64);
  __shared__ int ws[4];
  if (lane == 0) ws[wid] = s;
  __syncthreads();
  if (t == 0) bsum[b] = ws[0] + ws[1] + ws[2] + ws[3];
}

// B: 1 block x 128t; wave 0 scans deg block-sums, wave 1 scans cnt block-sums.
__global__ void k_bscan(const int* __restrict__ bsum, int* __restrict__ bscan,
                        int* __restrict__ rowOff, int* __restrict__ colOff) {
  const int t = threadIdx.x, w = t >> 6, lane = t & 63;
  const int s = (lane < 48) ? bsum[w * 48 + lane] : 0;
  int incl = s;
  #pragma unroll
  for (int off = 1; off < 64; off <<= 1) {
    int v = __shfl_up(incl, off, 64);
    if (lane >= off) incl += v;
  }
  if (lane < 48) bscan[w * 48 + lane] = incl - s;
  if (lane == 47) { if (w == 0) rowOff[NN] = incl; else colOff[NN] = incl; }
}

// C: 96 blocks x 256t; block-local scan (int4 + wave shfl + LDS) + bscan offset.
__global__ void k_scanout(const int* __restrict__ deg, const int* __restrict__ cnt,
                          const int* __restrict__ bscan,
                          int* __restrict__ rowOff, int* __restrict__ colOff) {
  const int b = blockIdx.x, t = threadIdx.x;
  const int lane = t & 63, wid = t >> 6;
  const bool isDeg = b < 48;
  const int base = (isDeg ? b : b - 48) * 1024 + t * 4;
  const int4 v = *(const int4*)((isDeg ? deg : cnt) + base);
  const int s = v.x + v.y + v.z + v.w;
  int incl = s;
  #pragma unroll
  for (int off = 1; off < 64; off <<= 1) {
    int u = __shfl_up(incl, off, 64);
    if (lane >= off) incl += u;
  }
  __shared__ int ws[4];
  if (lane == 63) ws[wid] = incl;
  __syncthreads();
  int woff = bscan[b];
  for (int i = 0; i < wid; ++i) woff += ws[i];
  const int e0 = incl - s + woff;
  int4 o;
  o.x = e0; o.y = e0 + v.x; o.z = o.y + v.y; o.w = o.z + v.z;
  *(int4*)((isDeg ? rowOff : colOff) + base) = o;
}

__global__ void k_fill(const int* __restrict__ ei,
                       const int* __restrict__ rowOff, const int* __restrict__ colOff,
                       int* __restrict__ rowFill, int* __restrict__ colFill,
                       int* __restrict__ rowCol, int* __restrict__ colSrc) {
  int e = blockIdx.x * 256 + threadIdx.x;
  if (e < NE) {
    int r = ei[e], c = ei[NE + e];
    int pr = atomicAdd(&rowFill[r], 1);
    rowCol[rowOff[r] + pr] = c;            // row-CSR: dst list per src (Laplacian)
    int pc = atomicAdd(&colFill[c], 1);
    colSrc[colOff[c] + pc] = r;            // col-CSR: src list per dst (SAGE agg)
  }
}

// xcomb[i,256:512] = x[i] - dinv[i]*sum_{row-CSR} dinv[c]*x[c]  (x read from xcomb[.,0:256])
__global__ void k_lap(u16* __restrict__ xcomb, const int* __restrict__ rowOff,
                      const int* __restrict__ rowCol, const float* __restrict__ dinv) {
  const int gid = blockIdx.x * 256 + threadIdx.x;
  const int wid = gid >> 6, lane = gid & 63;
  const int node = wid * 2 + (lane >> 5);
  const int f0 = (lane & 31) * 8;                   // 8 feats/lane, 32 lanes cover 256
  float xi[8]; unpack8(*(const uint4*)(xcomb + (size_t)node * KK + f0), xi);
  float a[8] = {};
  const int s0 = rowOff[node], s1 = rowOff[node + 1];
  for (int p = s0; p < s1; p += 4) {
    const int q1 = (p + 1 < s1) ? p + 1 : s1 - 1;
    const int q2 = (p + 2 < s1) ? p + 2 : s1 - 1;
    const int q3 = (p + 3 < s1) ? p + 3 : s1 - 1;
    const int c0 = rowCol[p], c1 = rowCol[q1], c2 = rowCol[q2], c3 = rowCol[q3];
    const float w0 = dinv[c0];
    const float w1 = (p + 1 < s1) ? dinv[c1] : 0.f;
    const float w2 = (p + 2 < s1) ? dinv[c2] : 0.f;
    const float w3 = (p + 3 < s1) ? dinv[c3] : 0.f;
    float g0[8], g1[8], g2[8], g3[8];
    unpack8(*(const uint4*)(xcomb + (size_t)c0 * KK + f0), g0);
    unpack8(*(const uint4*)(xcomb + (size_t)c1 * KK + f0), g1);
    unpack8(*(const uint4*)(xcomb + (size_t)c2 * KK + f0), g2);
    unpack8(*(const uint4*)(xcomb + (size_t)c3 * KK + f0), g3);
    #pragma unroll
    for (int j = 0; j < 8; ++j) a[j] += w0 * g0[j] + w1 * g1[j] + w2 * g2[j] + w3 * g3[j];
  }
  const float di = dinv[node];
  float l[8];
  #pragma unroll
  for (int j = 0; j < 8; ++j) l[j] = xi[j] - di * a[j];
  *(uint4*)(xcomb + (size_t)node * KK + ND + f0) = pack8(l);
}

// xcomb[i, 512:1024] = (1/cnt_i) * sum_{src->i} xcomb[src, 0:512]
// TWO nodes per wave interleaved (8 independent gathers in flight).
__global__ void k_aggx(u16* __restrict__ xcomb, const int* __restrict__ colOff,
                       const int* __restrict__ colSrc) {
  const int gid = blockIdx.x * 256 + threadIdx.x;
  const int wid = gid >> 6, lane = gid & 63;
  const int n0 = wid * 2, n1 = n0 + 1;
  const int f0 = lane * 8;                          // 64 lanes cover 512 cols
  const int sA = colOff[n0], sB = colOff[n0 + 1], eB = colOff[n1 + 1];
  const int dA = sB - sA, dB = eB - sB;
  float accA[8] = {}, accB[8] = {};
  const int T = (dA > dB) ? dA : dB;
  for (int t = 0; t < T; t += 4) {
    int cA[4], cB[4];
    float wA[4], wB[4];
    #pragma unroll
    for (int i = 0; i < 4; ++i) {
      const int o = t + i;
      int vA = colSrc[sA + ((o < dA) ? o : 0)];
      cA[i] = (o < dA) ? vA : 0;  wA[i] = (o < dA) ? 1.f : 0.f;
      int vB = colSrc[sB + ((o < dB) ? o : 0)];
      cB[i] = (o < dB) ? vB : 0;  wB[i] = (o < dB) ? 1.f : 0.f;
    }
    uint4 gA[4], gB[4];
    #pragma unroll
    for (int i = 0; i < 4; ++i) {
      gA[i] = *(const uint4*)(xcomb + (size_t)cA[i] * KK + f0);
      gB[i] = *(const uint4*)(xcomb + (size_t)cB[i] * KK + f0);
    }
    #pragma unroll
    for (int i = 0; i < 4; ++i) {
      float tmp[8];
      unpack8(gA[i], tmp);
      #pragma unroll
      for (int j = 0; j < 8; ++j) accA[j] += wA[i] * tmp[j];
      unpack8(gB[i], tmp);
      #pragma unroll
      for (int j = 0; j < 8; ++j) accB[j] += wB[i] * tmp[j];
    }
  }
  const float invA = (dA > 0) ? 1.0f / (float)dA : 1.0f;
  const float invB = (dB > 0) ? 1.0f / (float)dB : 1.0f;
  float rA[8], rB[8];
  #pragma unroll
  for (int j = 0; j < 8; ++j) { rA[j] = accA[j] * invA; rB[j] = accB[j] * invB; }
  *(uint4*)(xcomb + (size_t)n0 * KK + 512 + f0) = pack8(rA);
  *(uint4*)(xcomb + (size_t)n1 * KK + 512 + f0) = pack8(rB);
}

// ---------- GEMM1: h[M,512] = gelu(A[M,1024] @ B[512,1024]^T + b1), bf16 out ----------
// 128x128 tile, 8 waves (2x4, 64x32 sub-tiles), BK=64, single-buffer LDS 2-phase.
// 8-slot XOR swizzle both-sides; flip'd fragment offsets hoisted (static addresses).
__global__ __launch_bounds__(512, 4) void k_gemm1(const u16* __restrict__ A,
                                                  const u16* __restrict__ Bw,
                                                  const float* __restrict__ bias,
                                                  u16* __restrict__ Out) {
  __shared__ u16 As[128 * 64];
  __shared__ u16 Bs[128 * 64];
  const int tid = threadIdx.x;
  const int w = tid >> 6, lane = tid & 63;
  const int wr = w >> 2, wc = w & 3;       // 2 x 4 waves of 64x32

  const int cpx = gridDim.x >> 3;
  const int o = blockIdx.x;
  const int swz = (o & 7) * cpx + (o >> 3);
  const int bx = swz >> 2;                 // M tile
  const int by = swz & 3;                  // N tile

  const int lrow = lane >> 3;
  const int lcol = ((lane & 7) ^ lrow) * 8;          // XOR slot swizzle (row&7 = lrow)
  const u16* Ag = A  + (size_t)(bx * 128 + w * 16 + lrow) * KK + lcol;
  const u16* Bg = Bw + (size_t)(by * 128 + w * 16 + lrow) * KK + lcol;
  u16* Asl = As + w * 16 * 64;
  u16* Bsl = Bs + w * 16 * 64;

  const int kg = lane >> 4;
  const int slot = (kg ^ (lane & 7)) * 8;
  const int aoff0 = (wr * 64 + (lane & 15)) * 64 + slot;
  const int boff0 = (wc * 32 + (lane & 15)) * 64 + slot;
  const int aoff1 = aoff0 ^ 32;            // s2=1 half (bit5 flip, no carries)
  const int boff1 = boff0 ^ 32;

  f32x4 acc[4][2] = {};

  for (int kt = 0; kt < KK; kt += 64) {
    gld16(Ag + kt, Asl);
    gld16(Ag + kt + 8 * KK, Asl + 8 * 64);
    gld16(Bg + kt, Bsl);
    gld16(Bg + kt + 8 * KK, Bsl + 8 * 64);
    __syncthreads();
    {
      bf16x8 aF[4], bF[2];
      #pragma unroll
      for (int i = 0; i < 4; ++i) aF[i] = *(const bf16x8*)(As + aoff0 + i * 1024);
      #pragma unroll
      for (int i = 0; i < 2; ++i) bF[i] = *(const bf16x8*)(Bs + boff0 + i * 1024);
      #pragma unroll
      for (int mi = 0; mi < 4; ++mi)
        #pragma unroll
        for (int ni = 0; ni < 2; ++ni)
          acc[mi][ni] = __builtin_amdgcn_mfma_f32_16x16x32_bf16(aF[mi], bF[ni], acc[mi][ni], 0, 0, 0);
    }
    {
      bf16x8 aF[4], bF[2];
      #pragma unroll
      for (int i = 0; i < 4; ++i) aF[i] = *(const bf16x8*)(As + aoff1 + i * 1024);
      #pragma unroll
      for (int i = 0; i < 2; ++i) bF[i] = *(const bf16x8*)(Bs + boff1 + i * 1024);
      #pragma unroll
      for (int mi = 0; mi < 4; ++mi)
        #pragma unroll
        for (int ni = 0; ni < 2; ++ni)
          acc[mi][ni] = __builtin_amdgcn_mfma_f32_16x16x32_bf16(aF[mi], bF[ni], acc[mi][ni], 0, 0, 0);
    }
    __syncthreads();
  }

  // C/D layout: col = lane&15, row = (lane>>4)*4 + r
  const int lc = lane & 15, lr = (lane >> 4) * 4;
  const size_t r0 = (size_t)bx * 128 + wr * 64;
  const int cb = by * 128 + wc * 32;
  float bv[2];
  #pragma unroll
  for (int ni = 0; ni < 2; ++ni) bv[ni] = bias[cb + ni * 16 + lc];
  #pragma unroll
  for (int mi = 0; mi < 4; ++mi)
    #pragma unroll
    for (int ni = 0; ni < 2; ++ni)
      #pragma unroll
      for (int r = 0; r < 4; ++r) {
        float v = acc[mi][ni][r] + bv[ni];
        v = 0.5f * v * (1.0f + erff(v * 0.70710678118654752f));   // exact gelu
        Out[(r0 + mi * 16 + lr + r) * GD + (cb + ni * 16 + lc)] = f2bf(v);
      }
}

// ---------- GEMM2: out[1024,512] += split-K partials (f32 atomics) ----------
__global__ __launch_bounds__(256, 4) void k_gemm2(const u16* __restrict__ A,
                                                  const u16* __restrict__ Bw,
                                                  const float* __restrict__ bias,
                                                  float* __restrict__ Out) {
  __shared__ u16 As[128 * 64];
  __shared__ u16 Bs[128 * 64];
  const int tid = threadIdx.x;
  const int w = tid >> 6, lane = tid & 63;
  const int wr = w >> 1, wc = w & 1;
  const int bid = blockIdx.x;
  const int ks = bid >> 5;                 // 8 K-splits
  const int rr = bid & 31;
  const int bx = rr >> 2;                  // 8 M tiles
  const int by = rr & 3;                   // 4 N tiles

  const int lrow = lane >> 3;
  const int lcol = ((lane & 7) ^ lrow) * 8;
  const u16* Ag = A  + (size_t)(bx * 128 + w * 32 + lrow) * KK + lcol + ks * 128;
  const u16* Bg = Bw + (size_t)(by * 128 + w * 32 + lrow) * KK + lcol + ks * 128;
  u16* Asl = As + w * 32 * 64;
  u16* Bsl = Bs + w * 32 * 64;

  const int kg = lane >> 4;
  const int slot = (kg ^ (lane & 7)) * 8;
  const int aoff0 = (wr * 64 + (lane & 15)) * 64 + slot;
  const int boff0 = (wc * 64 + (lane & 15)) * 64 + slot;
  const int aoff1 = aoff0 ^ 32;
  const int boff1 = boff0 ^ 32;

  f32x4 acc[4][4] = {};

  #pragma unroll
  for (int kt = 0; kt < 128; kt += 64) {
    #pragma unroll
    for (int c = 0; c < 4; ++c) {
      gld16(Ag + kt + c * 8 * KK, Asl + c * 8 * 64);
      gld16(Bg + kt + c * 8 * KK, Bsl + c * 8 * 64);
    }
    __syncthreads();
    {
      bf16x8 aF[4], bF[4];
      #pragma unroll
      for (int i = 0; i < 4; ++i) aF[i] = *(const bf16x8*)(As + aoff0 + i * 1024);
      #pragma unroll
      for (int i = 0; i < 4; ++i) bF[i] = *(const bf16x8*)(Bs + boff0 + i * 1024);
      #pragma unroll
      for (int mi = 0; mi < 4; ++mi)
        #pragma unroll
        for (int ni = 0; ni < 4; ++ni)
          acc[mi][ni] = __builtin_amdgcn_mfma_f32_16x16x32_bf16(aF[mi], bF[ni], acc[mi][ni], 0, 0, 0);
    }
    {
      bf16x8 aF[4], bF[4];
      #pragma unroll
      for (int i = 0; i < 4; ++i) aF[i] = *(const bf16x8*)(As + aoff1 + i * 1024);
      #pragma unroll
      for (int i = 0; i < 4; ++i) bF[i] = *(const bf16x8*)(Bs + boff1 + i * 1024);
      #pragma unroll
      for (int mi = 0; mi < 4; ++mi)
        #pragma unroll
        for (int ni = 0; ni < 4; ++ni)
          acc[mi][ni] = __builtin_amdgcn_mfma_f32_16x16x32_bf16(aF[mi], bF[ni], acc[mi][ni], 0, 0, 0);
    }
    __syncthreads();
  }

  const int lc = lane & 15, lr = (lane >> 4) * 4;
  const size_t r0 = (size_t)bx * 128 + wr * 64;
  const int cb = by * 128 + wc * 64;
  float bv[4];
  #pragma unroll
  for (int ni = 0; ni < 4; ++ni) bv[ni] = (ks == 0) ? bias[cb + ni * 16 + lc] : 0.0f;
  #pragma unroll
  for (int mi = 0; mi < 4; ++mi)
    #pragma unroll
    for (int ni = 0; ni < 4; ++ni)
      #pragma unroll
      for (int r = 0; r < 4; ++r)
        atomicAdd(&Out[(r0 + mi * 16 + lr + r) * GD + (cb + ni * 16 + lc)],
                  acc[mi][ni][r] + bv[ni]);
}

// fused agg2 + pool -> h2cat[g, 0:512]=mean_pool(h), [512:1024]=mean_pool(mean_agg(h))
__global__ __launch_bounds__(512) void k_aggh(const u16* __restrict__ h, const int* __restrict__ colOff,
                                              const int* __restrict__ colSrc,
                                              u16* __restrict__ h2cat) {
  __shared__ float red[2][8][GD];                    // 32 KB
  const int g = blockIdx.x;
  const int t = threadIdx.x, w = t >> 6, lane = t & 63;
  const int f0 = lane * 8;
  float pr[8] = {}, pa[8] = {};
  for (int n = w; n < NS; n += 16) {                 // pairs (n, n+8); w in [0,8)
    const int node0 = g * NS + n, node1 = node0 + 8;
    float tmp[8];
    unpack8(*(const uint4*)(h + (size_t)node0 * GD + f0), tmp);
    #pragma unroll
    for (int j = 0; j < 8; ++j) pr[j] += tmp[j];
    unpack8(*(const uint4*)(h + (size_t)node1 * GD + f0), tmp);
    #pragma unroll
    for (int j = 0; j < 8; ++j) pr[j] += tmp[j];
    const int sA = colOff[node0], eA = colOff[node0 + 1];
    const int sB = colOff[node1], eB = colOff[node1 + 1];
    const int dA = eA - sA, dB = eB - sB;
    float accA[8] = {}, accB[8] = {};
    const int T = (dA > dB) ? dA : dB;
    for (int p = 0; p < T; p += 4) {
      int cA[4], cB[4];
      float wA[4], wB[4];
      #pragma unroll
      for (int i = 0; i < 4; ++i) {
        const int oo = p + i;
        int vA = colSrc[sA + ((oo < dA) ? oo : 0)];
        cA[i] = (oo < dA) ? vA : 0;  wA[i] = (oo < dA) ? 1.f : 0.f;
        int vB = colSrc[sB + ((oo < dB) ? oo : 0)];
        cB[i] = (oo < dB) ? vB : 0;  wB[i] = (oo < dB) ? 1.f : 0.f;
      }
      uint4 gA[4], gB[4];
      #pragma unroll
      for (int i = 0; i < 4; ++i) {
        gA[i] = *(const uint4*)(h + (size_t)cA[i] * GD + f0);
        gB[i] = *(const uint4*)(h + (size_t)cB[i] * GD + f0);
      }
      #pragma unroll
      for (int i = 0; i < 4; ++i) {
        unpack8(gA[i], tmp);
        #pragma unroll
        for (int j = 0; j < 8; ++j) accA[j] += wA[i] * tmp[j];
        unpack8(gB[i], tmp);
        #pragma unroll
        for (int j = 0; j < 8; ++j) accB[j] += wB[i] * tmp[j];
      }
    }
    const float invA = (dA > 0) ? 1.0f / (float)dA : 1.0f;
    const float invB = (dB > 0) ? 1.0f / (float)dB : 1.0f;
    #pragma unroll
    for (int j = 0; j < 8; ++j) pa[j] += accA[j] * invA;
    #pragma unroll
    for (int j = 0; j < 8; ++j) pa[j] += accB[j] * invB;
  }
  #pragma unroll
  for (int j = 0; j < 8; ++j) { red[0][w][f0 + j] = pr[j]; red[1][w][f0 + j] = pa[j]; }
  __syncthreads();
  if (t < 256) {
    const int f = t * 2;                             // 256 threads x 2 feats
    const float invS = 1.0f / (float)NS;
    float r0 = 0.f, r1 = 0.f, a0 = 0.f, a1 = 0.f;
    #pragma unroll
    for (int ww = 0; ww < 8; ++ww) {
      r0 += red[0][ww][f]; r1 += red[0][ww][f + 1];
      a0 += red[1][ww][f]; a1 += red[1][ww][f + 1];
    }
    r0 *= invS; r1 *= invS; a0 *= invS; a1 *= invS;
    *(unsigned*)(h2cat + (size_t)g * KK + f)       = (unsigned)f2bf(r0) | ((unsigned)f2bf(r1) << 16);
    *(unsigned*)(h2cat + (size_t)g * KK + 512 + f) = (unsigned)f2bf(a0) | ((unsigned)f2bf(a1) << 16);
  }
}

extern "C" void kernel_launch(void* const* d_in, const int* in_sizes, int n_in,
                              void* d_out, int out_size, void* d_ws, size_t ws_size,
                              hipStream_t stream) {
  const float* x   = (const float*)d_in[0];
  const int*   ei  = (const int*)d_in[1];           // int64 in reference -> int32 on device
  const float* Wl1 = (const float*)d_in[2];
  const float* Wr1 = (const float*)d_in[3];
  const float* b1  = (const float*)d_in[4];
  const float* Wl2 = (const float*)d_in[5];
  const float* Wr2 = (const float*)d_in[6];
  const float* b2  = (const float*)d_in[7];
  float* out = (float*)d_out;
  (void)in_sizes; (void)n_in; (void)out_size; (void)ws_size;

  // ---- workspace layout ----
  int* deg     = (int*)d_ws;                 // NN
  int* cnt     = deg + NN;                   // NN
  int* rowFill = cnt + NN;                   // NN
  int* colFill = rowFill + NN;               // NN   (deg..colFill = one memset region)
  int* rowOff  = colFill + NN;               // NN+64
  int* colOff  = rowOff + NN + 64;           // NN+64
  float* dinv  = (float*)(colOff + NN + 64); // NN
  int* rowCol  = (int*)(dinv + NN);          // NE
  int* colSrc  = rowCol + NE;                // NE
  int* bsum    = colSrc + NE;                // 96 (+pad)
  int* bscan   = bsum + 128;                 // 96 (+pad)
  u16* W1c     = (u16*)(bscan + 128);        // 512*1024 ([Wr1|Wl1] per row)
  u16* W2c     = W1c + 512 * KK;             // 512*1024
  u16* h2cat   = W2c + 512 * KK;             // 1024*1024
  u16* xcomb   = h2cat + (size_t)NB * KK;    // NN*1024 ([x|lap | agg] per row)
  u16* h       = xcomb + (size_t)NN * KK;    // NN*512

  hipMemsetAsync(deg, 0, sizeof(int) * 4 * NN, stream);
  hipMemsetAsync(out, 0, (size_t)NB * GD * sizeof(float), stream);   // split-K accumulator

  k_wxh<<<7936, 256, 0, stream>>>(ei, deg, cnt, Wr1, Wl1, Wr2, Wl2, W1c, W2c, x, xcomb);
  k_bsum<<<96, 256, 0, stream>>>(deg, cnt, dinv, bsum);
  k_bscan<<<1, 128, 0, stream>>>(bsum, bscan, rowOff, colOff);
  k_scanout<<<96, 256, 0, stream>>>(deg, cnt, bscan, rowOff, colOff);
  k_fill<<<NE / 256, 256, 0, stream>>>(ei, rowOff, colOff, rowFill, colFill, rowCol, colSrc);
  k_lap<<<(NN * 32) / 256, 256, 0, stream>>>(xcomb, rowOff, rowCol, dinv);
  k_aggx<<<(NN * 32) / 256, 256, 0, stream>>>(xcomb, colOff, colSrc);

  // h = gelu(xcomb @ W1c^T + b1): M=49152, N=512, K=1024
  k_gemm1<<<(NN / 128) * 4, 512, 0, stream>>>(xcomb, W1c, b1, h);

  k_aggh<<<NB, 512, 0, stream>>>(h, colOff, colSrc, h2cat);

  // out += split-K partials of h2cat @ W2c^T (+b2 from ks==0): M=1024, N=512
  k_gemm2<<<256, 256, 0, stream>>>(h2cat, W2c, b2, out);
}